// Round 4
// baseline (882.809 us; speedup 1.0000x reference)
//
#include <hip/hip_runtime.h>

#define N_NODES 50000
#define N_EDGES 800000
#define F_IN    64
#define HEADS   4
#define CH      32
#define K_DIM   128
#define NEG     0.2f

__device__ __forceinline__ float lrelu(float x) { return x > 0.f ? x : NEG * x; }

// ---------------------------------------------------------------------------
// K0: fold We*ae -> v[o][f] (o=0..3 layer1 heads, 4..7 layer2 heads), and
//     cbias = dot(b2, lin_w) + lin_b
// ---------------------------------------------------------------------------
__global__ void k0_fold(const float* __restrict__ We1, const float* __restrict__ ae1,
                        const float* __restrict__ We2, const float* __restrict__ ae2,
                        const float* __restrict__ b2,  const float* __restrict__ linw,
                        const float* __restrict__ linb,
                        float* __restrict__ v, float* __restrict__ cbias) {
    int t = threadIdx.x; // 256 threads
    for (int idx = t; idx < 512; idx += 256) {
        int o = idx >> 6, f = idx & 63;
        const float* We = (o < 4) ? We1 : We2;
        const float* ae = (o < 4) ? ae1 : ae2;
        int h = o & 3;
        float s = 0.f;
        for (int c = 0; c < CH; ++c)
            s += We[f * K_DIM + h * CH + c] * ae[h * CH + c];
        v[o * 64 + f] = s;
    }
    if (t == 0) {
        float s = 0.f;
        for (int k = 0; k < K_DIM; ++k) s += b2[k] * linw[k];
        *cbias = s + linb[0];
    }
}

// ---------------------------------------------------------------------------
// Kc: degree count from ei only.
// ---------------------------------------------------------------------------
__global__ void __launch_bounds__(256)
kc_count(const int* __restrict__ ei, int* __restrict__ cnt) {
    int e = blockIdx.x * 256 + threadIdx.x;
    if (e >= N_EDGES) return;
    atomicAdd(cnt + ei[N_EDGES + e], 1);
}

// ---------------------------------------------------------------------------
// K2: exclusive prefix scan of cnt -> starts[N+1], cursor. Single block,
//     shuffle-based.
// ---------------------------------------------------------------------------
__global__ void __launch_bounds__(1024)
k2_scan(const int* __restrict__ cnt, int* __restrict__ starts, int* __restrict__ cursor) {
    __shared__ int wsum[16];
    __shared__ int s_carry;
    int t = threadIdx.x;
    int lane = t & 63, wid = t >> 6;
    if (t == 0) s_carry = 0;
    __syncthreads();
    for (int base = 0; base < N_NODES; base += 1024) {
        int i = base + t;
        int v = (i < N_NODES) ? cnt[i] : 0;
        int sc = v; // inclusive wave scan
#pragma unroll
        for (int s = 1; s < 64; s <<= 1) {
            int u = __shfl_up(sc, s, 64);
            if (lane >= s) sc += u;
        }
        if (lane == 63) wsum[wid] = sc;
        __syncthreads();
        if (wid == 0 && lane < 16) {
            int ws = wsum[lane];
#pragma unroll
            for (int s = 1; s < 16; s <<= 1) {
                int u = __shfl_up(ws, s, 64);
                if (lane >= s) ws += u;
            }
            wsum[lane] = ws;
        }
        __syncthreads();
        int carry = s_carry;
        int woff = (wid == 0) ? 0 : wsum[wid - 1];
        int excl = carry + woff + sc - v;
        if (i < N_NODES) { starts[i] = excl; cursor[i] = excl; }
        __syncthreads();
        if (t == 0) s_carry = carry + wsum[15];
    }
    __syncthreads();
    if (t == 0) starts[N_NODES] = s_carry;
}

// ---------------------------------------------------------------------------
// K1: per-edge a_e, thread-per-edge with a 2-edge register tile. v in LDS,
//     read as broadcast float4 (no shuffles, no cross-lane reduce). Scatters
//     directly into dst-sorted lists.
// ---------------------------------------------------------------------------
__global__ void __launch_bounds__(256)
k1_edge(const float* __restrict__ ea, const int* __restrict__ ei,
        const float* __restrict__ v, int* __restrict__ cursor,
        int* __restrict__ el_src, float4* __restrict__ el_ae1,
        float4* __restrict__ el_ae2) {
    __shared__ float sv[512];
    int t = threadIdx.x;
    sv[t] = v[t];
    sv[t + 256] = v[t + 256];
    __syncthreads();
    int lane = t & 63;
    int e0 = blockIdx.x * 512 + (t >> 6) * 128 + lane;
    int e1 = e0 + 64;
    bool v0 = e0 < N_EDGES, v1 = e1 < N_EDGES;
    float acc0[8] = {0, 0, 0, 0, 0, 0, 0, 0};
    float acc1[8] = {0, 0, 0, 0, 0, 0, 0, 0};
    const float4 z4 = make_float4(0, 0, 0, 0);
#pragma unroll
    for (int c = 0; c < 16; ++c) {
        float4 x0 = v0 ? *reinterpret_cast<const float4*>(ea + (size_t)e0 * F_IN + c * 4) : z4;
        float4 x1 = v1 ? *reinterpret_cast<const float4*>(ea + (size_t)e1 * F_IN + c * 4) : z4;
#pragma unroll
        for (int o = 0; o < 8; ++o) {
            float4 vv = *reinterpret_cast<const float4*>(sv + o * 64 + c * 4);
            acc0[o] += x0.x * vv.x + x0.y * vv.y + x0.z * vv.z + x0.w * vv.w;
            acc1[o] += x1.x * vv.x + x1.y * vv.y + x1.z * vv.z + x1.w * vv.w;
        }
    }
    if (v0) {
        int dst = ei[N_EDGES + e0];
        int pos = atomicAdd(cursor + dst, 1);
        el_src[pos] = ei[e0];
        el_ae1[pos] = make_float4(acc0[0], acc0[1], acc0[2], acc0[3]);
        el_ae2[pos] = make_float4(acc0[4], acc0[5], acc0[6], acc0[7]);
    }
    if (v1) {
        int dst = ei[N_EDGES + e1];
        int pos = atomicAdd(cursor + dst, 1);
        el_src[pos] = ei[e1];
        el_ae1[pos] = make_float4(acc1[0], acc1[1], acc1[2], acc1[3]);
        el_ae2[pos] = make_float4(acc1[4], acc1[5], acc1[6], acc1[7]);
    }
}

// ---------------------------------------------------------------------------
// K4: layer-1 node projection, register-tiled 4 nodes x 4 cols per thread.
//     Block = 32 nodes x 128 cols, 256 threads. x-tile transposed in LDS
//     (pad +1: conflict-free stage, 8-distinct-bank reads).
//     tid = nq*32 + kq: nq in [0,8) node-quad, kq in [0,32) col-quad.
// ---------------------------------------------------------------------------
__global__ void __launch_bounds__(256)
k4_proj1(const float* __restrict__ x, const float* __restrict__ W,
         const float* __restrict__ asf, const float* __restrict__ adf,
         float* __restrict__ hp, float* __restrict__ asn, float* __restrict__ adn) {
    __shared__ float sxT[F_IN * 33]; // [f][i], i in [0,32), pad 1
    int t = threadIdx.x;
    int n0 = blockIdx.x * 32;
    // stage: coalesced read of x rows, transposed store (banks (f+i)%32: free)
    {
        int f = t & 63, i0 = t >> 6;
#pragma unroll
        for (int s = 0; s < 8; ++s) {
            int i = i0 + s * 4;
            int n = n0 + i;
            sxT[f * 33 + i] = (n < N_NODES) ? x[(size_t)n * F_IN + f] : 0.f;
        }
    }
    __syncthreads();
    int kq = t & 31, nq = t >> 5;
    float acc[4][4] = {};
    for (int f = 0; f < F_IN; ++f) {
        float a0 = sxT[f * 33 + nq * 4 + 0];
        float a1 = sxT[f * 33 + nq * 4 + 1];
        float a2 = sxT[f * 33 + nq * 4 + 2];
        float a3 = sxT[f * 33 + nq * 4 + 3];
        float4 w4 = *reinterpret_cast<const float4*>(W + (size_t)f * K_DIM + kq * 4);
        acc[0][0] += a0 * w4.x; acc[0][1] += a0 * w4.y; acc[0][2] += a0 * w4.z; acc[0][3] += a0 * w4.w;
        acc[1][0] += a1 * w4.x; acc[1][1] += a1 * w4.y; acc[1][2] += a1 * w4.z; acc[1][3] += a1 * w4.w;
        acc[2][0] += a2 * w4.x; acc[2][1] += a2 * w4.y; acc[2][2] += a2 * w4.z; acc[2][3] += a2 * w4.w;
        acc[3][0] += a3 * w4.x; acc[3][1] += a3 * w4.y; acc[3][2] += a3 * w4.z; acc[3][3] += a3 * w4.w;
    }
    int head = kq >> 3;                 // cols kq*4..kq*4+3 all in head kq/8
    float4 va = *reinterpret_cast<const float4*>(asf + kq * 4);
    float4 vd = *reinterpret_cast<const float4*>(adf + kq * 4);
#pragma unroll
    for (int i = 0; i < 4; ++i) {
        int n = n0 + nq * 4 + i;
        if (n < N_NODES)
            *reinterpret_cast<float4*>(hp + (size_t)n * K_DIM + kq * 4) =
                make_float4(acc[i][0], acc[i][1], acc[i][2], acc[i][3]);
        float s = acc[i][0] * va.x + acc[i][1] * va.y + acc[i][2] * va.z + acc[i][3] * va.w;
        float d = acc[i][0] * vd.x + acc[i][1] * vd.y + acc[i][2] * vd.z + acc[i][3] * vd.w;
#pragma unroll
        for (int m = 1; m < 8; m <<= 1) {
            s += __shfl_xor(s, m, 8);
            d += __shfl_xor(d, m, 8);
        }
        if ((kq & 7) == 0 && n < N_NODES) {
            asn[(size_t)n * 4 + head] = s;
            adn[(size_t)n * 4 + head] = d;
        }
    }
}

// ---------------------------------------------------------------------------
// K5: layer-1 gather aggregation. One 64-lane wave per node; lane owns 2
//     output columns. No atomics.
// ---------------------------------------------------------------------------
__global__ void __launch_bounds__(256)
k5_agg1(const int* __restrict__ starts, const int* __restrict__ el_src,
        const float* __restrict__ el_ae1,
        const float* __restrict__ asn, const float* __restrict__ adn,
        const float* __restrict__ hp, const float* __restrict__ b1,
        float* __restrict__ x2) {
    int t = threadIdx.x;
    int lane = t & 63;
    int node = blockIdx.x * 4 + (t >> 6);
    if (node >= N_NODES) return;
    int s = starts[node], e = starts[node + 1];
    int head = lane >> 4; // col pair = lane*2; head = (lane*2)>>5
    float adv = adn[(size_t)node * 4 + head];
    float accx = 0.f, accy = 0.f, dsum = 0.f, aesum = 0.f;
    for (int j = s; j < e; ++j) {
        int src = el_src[j];
        float ae = el_ae1[(size_t)j * 4 + head];
        float av = asn[(size_t)src * 4 + head];
        float ex = __expf(lrelu(av + adv + ae));
        float2 hv = *reinterpret_cast<const float2*>(hp + (size_t)src * K_DIM + lane * 2);
        accx += ex * hv.x;
        accy += ex * hv.y;
        dsum += ex;
        aesum += ae;
    }
    float deg = (float)(e - s);
    float al = aesum / fmaxf(deg, 1.f); // self-loop a_e = mean of incoming
    float exl = __expf(lrelu(asn[(size_t)node * 4 + head] + adv + al));
    float2 hv = *reinterpret_cast<const float2*>(hp + (size_t)node * K_DIM + lane * 2);
    accx += exl * hv.x;
    accy += exl * hv.y;
    dsum += exl;
    float2 bb = *reinterpret_cast<const float2*>(b1 + lane * 2);
    float2 o;
    o.x = fmaxf(accx / dsum + bb.x, 0.f);
    o.y = fmaxf(accy / dsum + bb.y, 0.f);
    *reinterpret_cast<float2*>(x2 + (size_t)node * K_DIM + lane * 2) = o;
}

// ---------------------------------------------------------------------------
// K6: layer-2 node projection, register-tiled like K4 (F=128). Outputs packed
//     asg[n] = {a_s2[4], g[4]} + adn2. h2p never materialized.
// ---------------------------------------------------------------------------
__global__ void __launch_bounds__(256)
k6_proj2(const float* __restrict__ x2, const float* __restrict__ W2,
         const float* __restrict__ asf, const float* __restrict__ adf,
         const float* __restrict__ linw,
         float* __restrict__ asg, float* __restrict__ adn) {
    __shared__ float sxT[K_DIM * 33]; // [f][i], i in [0,32), pad 1
    int t = threadIdx.x;
    int n0 = blockIdx.x * 32;
    {
        int f = t & 127, i0 = t >> 7;
#pragma unroll
        for (int s = 0; s < 16; ++s) {
            int i = i0 + s * 2;
            int n = n0 + i;
            sxT[f * 33 + i] = (n < N_NODES) ? x2[(size_t)n * K_DIM + f] : 0.f;
        }
    }
    __syncthreads();
    int kq = t & 31, nq = t >> 5;
    float acc[4][4] = {};
    for (int f = 0; f < K_DIM; ++f) {
        float a0 = sxT[f * 33 + nq * 4 + 0];
        float a1 = sxT[f * 33 + nq * 4 + 1];
        float a2 = sxT[f * 33 + nq * 4 + 2];
        float a3 = sxT[f * 33 + nq * 4 + 3];
        float4 w4 = *reinterpret_cast<const float4*>(W2 + (size_t)f * K_DIM + kq * 4);
        acc[0][0] += a0 * w4.x; acc[0][1] += a0 * w4.y; acc[0][2] += a0 * w4.z; acc[0][3] += a0 * w4.w;
        acc[1][0] += a1 * w4.x; acc[1][1] += a1 * w4.y; acc[1][2] += a1 * w4.z; acc[1][3] += a1 * w4.w;
        acc[2][0] += a2 * w4.x; acc[2][1] += a2 * w4.y; acc[2][2] += a2 * w4.z; acc[2][3] += a2 * w4.w;
        acc[3][0] += a3 * w4.x; acc[3][1] += a3 * w4.y; acc[3][2] += a3 * w4.z; acc[3][3] += a3 * w4.w;
    }
    int head = kq >> 3;
    float4 va = *reinterpret_cast<const float4*>(asf + kq * 4);
    float4 vd = *reinterpret_cast<const float4*>(adf + kq * 4);
    float4 vg = *reinterpret_cast<const float4*>(linw + kq * 4);
#pragma unroll
    for (int i = 0; i < 4; ++i) {
        int n = n0 + nq * 4 + i;
        float s = acc[i][0] * va.x + acc[i][1] * va.y + acc[i][2] * va.z + acc[i][3] * va.w;
        float d = acc[i][0] * vd.x + acc[i][1] * vd.y + acc[i][2] * vd.z + acc[i][3] * vd.w;
        float g = acc[i][0] * vg.x + acc[i][1] * vg.y + acc[i][2] * vg.z + acc[i][3] * vg.w;
#pragma unroll
        for (int m = 1; m < 8; m <<= 1) {
            s += __shfl_xor(s, m, 8);
            d += __shfl_xor(d, m, 8);
            g += __shfl_xor(g, m, 8);
        }
        if ((kq & 7) == 0 && n < N_NODES) {
            asg[(size_t)n * 8 + head] = s;
            asg[(size_t)n * 8 + 4 + head] = g;
            adn[(size_t)n * 4 + head] = d;
        }
    }
}

// ---------------------------------------------------------------------------
// K7: layer-2 gather: 16-lane group per node, lanes stride the edge list.
// ---------------------------------------------------------------------------
__global__ void __launch_bounds__(256)
k7_l2(const int* __restrict__ starts, const int* __restrict__ el_src,
      const float4* __restrict__ el_ae2, const float* __restrict__ asg,
      const float* __restrict__ adn, const float* __restrict__ cbias,
      float* __restrict__ out) {
    int t = threadIdx.x;
    int g16 = t & 15;
    int node = blockIdx.x * 16 + (t >> 4);
    if (node >= N_NODES) return;
    int s = starts[node], e = starts[node + 1];
    float4 ad4 = *reinterpret_cast<const float4*>(adn + (size_t)node * 4);
    float4 dsum = make_float4(0, 0, 0, 0);
    float4 gsum = make_float4(0, 0, 0, 0);
    float4 aesum = make_float4(0, 0, 0, 0);
    for (int j = s + g16; j < e; j += 16) {
        int src = el_src[j];
        float4 ae4 = el_ae2[j];
        const float* ap = asg + (size_t)src * 8;
        float4 as4 = *reinterpret_cast<const float4*>(ap);
        float4 g4  = *reinterpret_cast<const float4*>(ap + 4);
        float e0 = __expf(lrelu(as4.x + ad4.x + ae4.x));
        float e1 = __expf(lrelu(as4.y + ad4.y + ae4.y));
        float e2 = __expf(lrelu(as4.z + ad4.z + ae4.z));
        float e3 = __expf(lrelu(as4.w + ad4.w + ae4.w));
        dsum.x += e0; dsum.y += e1; dsum.z += e2; dsum.w += e3;
        gsum.x += e0 * g4.x; gsum.y += e1 * g4.y; gsum.z += e2 * g4.z; gsum.w += e3 * g4.w;
        aesum.x += ae4.x; aesum.y += ae4.y; aesum.z += ae4.z; aesum.w += ae4.w;
    }
#pragma unroll
    for (int m = 1; m < 16; m <<= 1) {
        dsum.x += __shfl_xor(dsum.x, m, 16);  dsum.y += __shfl_xor(dsum.y, m, 16);
        dsum.z += __shfl_xor(dsum.z, m, 16);  dsum.w += __shfl_xor(dsum.w, m, 16);
        gsum.x += __shfl_xor(gsum.x, m, 16);  gsum.y += __shfl_xor(gsum.y, m, 16);
        gsum.z += __shfl_xor(gsum.z, m, 16);  gsum.w += __shfl_xor(gsum.w, m, 16);
        aesum.x += __shfl_xor(aesum.x, m, 16); aesum.y += __shfl_xor(aesum.y, m, 16);
        aesum.z += __shfl_xor(aesum.z, m, 16); aesum.w += __shfl_xor(aesum.w, m, 16);
    }
    if (g16 == 0) {
        float deg = fmaxf((float)(e - s), 1.f);
        const float* ap = asg + (size_t)node * 8;
        float4 mas = *reinterpret_cast<const float4*>(ap);
        float4 mg  = *reinterpret_cast<const float4*>(ap + 4);
        float r = cbias[0];
        float e0;
        e0 = __expf(lrelu(mas.x + ad4.x + aesum.x / deg)); r += (gsum.x + e0 * mg.x) / (dsum.x + e0);
        e0 = __expf(lrelu(mas.y + ad4.y + aesum.y / deg)); r += (gsum.y + e0 * mg.y) / (dsum.y + e0);
        e0 = __expf(lrelu(mas.z + ad4.z + aesum.z / deg)); r += (gsum.z + e0 * mg.z) / (dsum.z + e0);
        e0 = __expf(lrelu(mas.w + ad4.w + aesum.w / deg)); r += (gsum.w + e0 * mg.w) / (dsum.w + e0);
        out[node] = r;
    }
}

// ---------------------------------------------------------------------------
extern "C" void kernel_launch(void* const* d_in, const int* in_sizes, int n_in,
                              void* d_out, int out_size, void* d_ws, size_t ws_size,
                              hipStream_t stream) {
    (void)in_sizes; (void)n_in; (void)out_size;
    const float* x    = (const float*)d_in[0];
    const float* ea   = (const float*)d_in[1];
    const float* W1   = (const float*)d_in[2];
    const float* as1  = (const float*)d_in[3];
    const float* ad1  = (const float*)d_in[4];
    const float* We1  = (const float*)d_in[5];
    const float* ae1  = (const float*)d_in[6];
    const float* b1   = (const float*)d_in[7];
    const float* W2   = (const float*)d_in[8];
    const float* as2  = (const float*)d_in[9];
    const float* ad2  = (const float*)d_in[10];
    const float* We2  = (const float*)d_in[11];
    const float* ae2  = (const float*)d_in[12];
    const float* b2   = (const float*)d_in[13];
    const float* linw = (const float*)d_in[14];
    const float* linb = (const float*)d_in[15];
    const int*   ei   = (const int*)d_in[16];
    float* out = (float*)d_out;
    float* ws  = (float*)d_ws;

    size_t off = 0;
    float* h1p   = ws + off; off += (size_t)N_NODES * K_DIM;
    float* x2    = ws + off; off += (size_t)N_NODES * K_DIM;
    float* asn1  = ws + off; off += (size_t)N_NODES * 4;
    float* adn1  = ws + off; off += (size_t)N_NODES * 4;
    float* asg2  = ws + off; off += (size_t)N_NODES * 8;
    float* adn2  = ws + off; off += (size_t)N_NODES * 4;
    float* vbuf  = ws + off; off += 512;
    float* cbias = ws + off; off += 64;
    int* starts  = (int*)(ws + off); off += (size_t)N_NODES + 8;
    int* cursor  = (int*)(ws + off); off += (size_t)N_NODES;
    int* el_src  = (int*)(ws + off); off += (size_t)N_EDGES;
    float* elae1 = ws + off; off += (size_t)N_EDGES * 4;
    float* elae2 = ws + off; off += (size_t)N_EDGES * 4;
    int* cnt     = (int*)(ws + off); off += (size_t)N_NODES;

    if (ws_size < off * sizeof(float)) return; // workspace too small: fail visibly

    hipMemsetAsync(cnt, 0, N_NODES * sizeof(int), stream);

    k0_fold<<<1, 256, 0, stream>>>(We1, ae1, We2, ae2, b2, linw, linb, vbuf, cbias);
    kc_count<<<(N_EDGES + 255) / 256, 256, 0, stream>>>(ei, cnt);
    k2_scan<<<1, 1024, 0, stream>>>(cnt, starts, cursor);
    k1_edge<<<(N_EDGES + 511) / 512, 256, 0, stream>>>(ea, ei, vbuf, cursor, el_src,
                                                       (float4*)elae1, (float4*)elae2);
    k4_proj1<<<(N_NODES + 31) / 32, 256, 0, stream>>>(x, W1, as1, ad1, h1p, asn1, adn1);
    k5_agg1<<<(N_NODES + 3) / 4, 256, 0, stream>>>(starts, el_src, elae1,
                                                   asn1, adn1, h1p, b1, x2);
    k6_proj2<<<(N_NODES + 31) / 32, 256, 0, stream>>>(x2, W2, as2, ad2, linw, asg2, adn2);
    k7_l2<<<(N_NODES + 15) / 16, 256, 0, stream>>>(starts, el_src, (const float4*)elae2,
                                                   asg2, adn2, cbias, out);
}

// Round 5
// 395.464 us; speedup vs baseline: 2.2323x; 2.2323x over previous
//
#include <hip/hip_runtime.h>

#define N_NODES 50000
#define N_EDGES 800000
#define F_IN    64
#define HEADS   4
#define CH      32
#define K_DIM   128
#define NEG     0.2f

__device__ __forceinline__ float lrelu(float x) { return x > 0.f ? x : NEG * x; }

// ---------------------------------------------------------------------------
// K0: fold We*ae -> v[o][f] (o=0..3 layer1 heads, 4..7 layer2 heads), and
//     cbias = dot(b2, lin_w) + lin_b
// ---------------------------------------------------------------------------
__global__ void k0_fold(const float* __restrict__ We1, const float* __restrict__ ae1,
                        const float* __restrict__ We2, const float* __restrict__ ae2,
                        const float* __restrict__ b2,  const float* __restrict__ linw,
                        const float* __restrict__ linb,
                        float* __restrict__ v, float* __restrict__ cbias) {
    int t = threadIdx.x; // 256 threads
    for (int idx = t; idx < 512; idx += 256) {
        int o = idx >> 6, f = idx & 63;
        const float* We = (o < 4) ? We1 : We2;
        const float* ae = (o < 4) ? ae1 : ae2;
        int h = o & 3;
        float s = 0.f;
        for (int c = 0; c < CH; ++c)
            s += We[f * K_DIM + h * CH + c] * ae[h * CH + c];
        v[o * 64 + f] = s;
    }
    if (t == 0) {
        float s = 0.f;
        for (int k = 0; k < K_DIM; ++k) s += b2[k] * linw[k];
        *cbias = s + linb[0];
    }
}

// ---------------------------------------------------------------------------
// Kc: degree count from ei only.
// ---------------------------------------------------------------------------
__global__ void __launch_bounds__(256)
kc_count(const int* __restrict__ ei, int* __restrict__ cnt) {
    int e = blockIdx.x * 256 + threadIdx.x;
    if (e >= N_EDGES) return;
    atomicAdd(cnt + ei[N_EDGES + e], 1);
}

// ---------------------------------------------------------------------------
// K2: exclusive prefix scan of cnt -> starts[N+1], cursor. Single block,
//     shuffle-based.
// ---------------------------------------------------------------------------
__global__ void __launch_bounds__(1024)
k2_scan(const int* __restrict__ cnt, int* __restrict__ starts, int* __restrict__ cursor) {
    __shared__ int wsum[16];
    __shared__ int s_carry;
    int t = threadIdx.x;
    int lane = t & 63, wid = t >> 6;
    if (t == 0) s_carry = 0;
    __syncthreads();
    for (int base = 0; base < N_NODES; base += 1024) {
        int i = base + t;
        int v = (i < N_NODES) ? cnt[i] : 0;
        int sc = v; // inclusive wave scan
#pragma unroll
        for (int s = 1; s < 64; s <<= 1) {
            int u = __shfl_up(sc, s, 64);
            if (lane >= s) sc += u;
        }
        if (lane == 63) wsum[wid] = sc;
        __syncthreads();
        if (wid == 0 && lane < 16) {
            int ws = wsum[lane];
#pragma unroll
            for (int s = 1; s < 16; s <<= 1) {
                int u = __shfl_up(ws, s, 64);
                if (lane >= s) ws += u;
            }
            wsum[lane] = ws;
        }
        __syncthreads();
        int carry = s_carry;
        int woff = (wid == 0) ? 0 : wsum[wid - 1];
        int excl = carry + woff + sc - v;
        if (i < N_NODES) { starts[i] = excl; cursor[i] = excl; }
        __syncthreads();
        if (t == 0) s_carry = carry + wsum[15];
    }
    __syncthreads();
    if (t == 0) starts[N_NODES] = s_carry;
}

// ---------------------------------------------------------------------------
// K1: per-edge a_e, thread-per-edge, acc[8] in registers, v broadcast from
//     LDS as float4 (no shuffles). unroll 4 bounds in-flight loads so VGPRs
//     stay low (R4 lesson: full unroll + 2-edge tile -> 256 VGPR + spills).
//     N_EDGES % 256 == 0: no tail predicate.
// ---------------------------------------------------------------------------
__global__ void __launch_bounds__(256)
k1_edge(const float* __restrict__ ea, const int* __restrict__ ei,
        const float* __restrict__ v, int* __restrict__ cursor,
        int* __restrict__ el_src, float4* __restrict__ el_ae1,
        float4* __restrict__ el_ae2) {
    __shared__ float sv[512];
    int t = threadIdx.x;
    sv[t] = v[t];
    sv[t + 256] = v[t + 256];
    __syncthreads();
    int eid = blockIdx.x * 256 + t;
    const float* row = ea + (size_t)eid * F_IN;
    float acc[8] = {0, 0, 0, 0, 0, 0, 0, 0};
#pragma unroll 4
    for (int c = 0; c < 16; ++c) {
        float4 x4 = *reinterpret_cast<const float4*>(row + c * 4);
#pragma unroll
        for (int o = 0; o < 8; ++o) {
            float4 vv = *reinterpret_cast<const float4*>(sv + o * 64 + c * 4);
            acc[o] = fmaf(x4.x, vv.x, fmaf(x4.y, vv.y, fmaf(x4.z, vv.z, fmaf(x4.w, vv.w, acc[o]))));
        }
    }
    int dst = ei[N_EDGES + eid];
    int src = ei[eid];
    int pos = atomicAdd(cursor + dst, 1);
    el_src[pos] = src;
    el_ae1[pos] = make_float4(acc[0], acc[1], acc[2], acc[3]);
    el_ae2[pos] = make_float4(acc[4], acc[5], acc[6], acc[7]);
}

// ---------------------------------------------------------------------------
// K4: layer-1 node projection, register-tiled 4 nodes x 4 cols per thread.
//     Block = 32 nodes x 128 cols, 256 threads. x-tile transposed in LDS.
// ---------------------------------------------------------------------------
__global__ void __launch_bounds__(256)
k4_proj1(const float* __restrict__ x, const float* __restrict__ W,
         const float* __restrict__ asf, const float* __restrict__ adf,
         float* __restrict__ hp, float* __restrict__ asn, float* __restrict__ adn) {
    __shared__ float sxT[F_IN * 33]; // [f][i], i in [0,32), pad 1
    int t = threadIdx.x;
    int n0 = blockIdx.x * 32;
    {
        int f = t & 63, i0 = t >> 6;
#pragma unroll
        for (int s = 0; s < 8; ++s) {
            int i = i0 + s * 4;
            int n = n0 + i;
            sxT[f * 33 + i] = (n < N_NODES) ? x[(size_t)n * F_IN + f] : 0.f;
        }
    }
    __syncthreads();
    int kq = t & 31, nq = t >> 5;
    float acc[4][4] = {};
    for (int f = 0; f < F_IN; ++f) {
        float a0 = sxT[f * 33 + nq * 4 + 0];
        float a1 = sxT[f * 33 + nq * 4 + 1];
        float a2 = sxT[f * 33 + nq * 4 + 2];
        float a3 = sxT[f * 33 + nq * 4 + 3];
        float4 w4 = *reinterpret_cast<const float4*>(W + (size_t)f * K_DIM + kq * 4);
        acc[0][0] += a0 * w4.x; acc[0][1] += a0 * w4.y; acc[0][2] += a0 * w4.z; acc[0][3] += a0 * w4.w;
        acc[1][0] += a1 * w4.x; acc[1][1] += a1 * w4.y; acc[1][2] += a1 * w4.z; acc[1][3] += a1 * w4.w;
        acc[2][0] += a2 * w4.x; acc[2][1] += a2 * w4.y; acc[2][2] += a2 * w4.z; acc[2][3] += a2 * w4.w;
        acc[3][0] += a3 * w4.x; acc[3][1] += a3 * w4.y; acc[3][2] += a3 * w4.z; acc[3][3] += a3 * w4.w;
    }
    int head = kq >> 3;
    float4 va = *reinterpret_cast<const float4*>(asf + kq * 4);
    float4 vd = *reinterpret_cast<const float4*>(adf + kq * 4);
#pragma unroll
    for (int i = 0; i < 4; ++i) {
        int n = n0 + nq * 4 + i;
        if (n < N_NODES)
            *reinterpret_cast<float4*>(hp + (size_t)n * K_DIM + kq * 4) =
                make_float4(acc[i][0], acc[i][1], acc[i][2], acc[i][3]);
        float s = acc[i][0] * va.x + acc[i][1] * va.y + acc[i][2] * va.z + acc[i][3] * va.w;
        float d = acc[i][0] * vd.x + acc[i][1] * vd.y + acc[i][2] * vd.z + acc[i][3] * vd.w;
#pragma unroll
        for (int m = 1; m < 8; m <<= 1) {
            s += __shfl_xor(s, m, 8);
            d += __shfl_xor(d, m, 8);
        }
        if ((kq & 7) == 0 && n < N_NODES) {
            asn[(size_t)n * 4 + head] = s;
            adn[(size_t)n * 4 + head] = d;
        }
    }
}

// ---------------------------------------------------------------------------
// K5: layer-1 gather aggregation. One 64-lane wave per node; lane owns 2
//     output columns. No atomics.
// ---------------------------------------------------------------------------
__global__ void __launch_bounds__(256)
k5_agg1(const int* __restrict__ starts, const int* __restrict__ el_src,
        const float* __restrict__ el_ae1,
        const float* __restrict__ asn, const float* __restrict__ adn,
        const float* __restrict__ hp, const float* __restrict__ b1,
        float* __restrict__ x2) {
    int t = threadIdx.x;
    int lane = t & 63;
    int node = blockIdx.x * 4 + (t >> 6);
    if (node >= N_NODES) return;
    int s = starts[node], e = starts[node + 1];
    int head = lane >> 4; // col pair = lane*2; head = (lane*2)>>5
    float adv = adn[(size_t)node * 4 + head];
    float accx = 0.f, accy = 0.f, dsum = 0.f, aesum = 0.f;
    for (int j = s; j < e; ++j) {
        int src = el_src[j];
        float ae = el_ae1[(size_t)j * 4 + head];
        float av = asn[(size_t)src * 4 + head];
        float ex = __expf(lrelu(av + adv + ae));
        float2 hv = *reinterpret_cast<const float2*>(hp + (size_t)src * K_DIM + lane * 2);
        accx += ex * hv.x;
        accy += ex * hv.y;
        dsum += ex;
        aesum += ae;
    }
    float deg = (float)(e - s);
    float al = aesum / fmaxf(deg, 1.f); // self-loop a_e = mean of incoming
    float exl = __expf(lrelu(asn[(size_t)node * 4 + head] + adv + al));
    float2 hv = *reinterpret_cast<const float2*>(hp + (size_t)node * K_DIM + lane * 2);
    accx += exl * hv.x;
    accy += exl * hv.y;
    dsum += exl;
    float2 bb = *reinterpret_cast<const float2*>(b1 + lane * 2);
    float2 o;
    o.x = fmaxf(accx / dsum + bb.x, 0.f);
    o.y = fmaxf(accy / dsum + bb.y, 0.f);
    *reinterpret_cast<float2*>(x2 + (size_t)node * K_DIM + lane * 2) = o;
}

// ---------------------------------------------------------------------------
// K6: layer-2 node projection, register-tiled like K4 (F=128). Outputs packed
//     asg[n] = {a_s2[4], g[4]} + adn2. h2p never materialized.
// ---------------------------------------------------------------------------
__global__ void __launch_bounds__(256)
k6_proj2(const float* __restrict__ x2, const float* __restrict__ W2,
         const float* __restrict__ asf, const float* __restrict__ adf,
         const float* __restrict__ linw,
         float* __restrict__ asg, float* __restrict__ adn) {
    __shared__ float sxT[K_DIM * 33]; // [f][i], i in [0,32), pad 1
    int t = threadIdx.x;
    int n0 = blockIdx.x * 32;
    {
        int f = t & 127, i0 = t >> 7;
#pragma unroll
        for (int s = 0; s < 16; ++s) {
            int i = i0 + s * 2;
            int n = n0 + i;
            sxT[f * 33 + i] = (n < N_NODES) ? x2[(size_t)n * K_DIM + f] : 0.f;
        }
    }
    __syncthreads();
    int kq = t & 31, nq = t >> 5;
    float acc[4][4] = {};
    for (int f = 0; f < K_DIM; ++f) {
        float a0 = sxT[f * 33 + nq * 4 + 0];
        float a1 = sxT[f * 33 + nq * 4 + 1];
        float a2 = sxT[f * 33 + nq * 4 + 2];
        float a3 = sxT[f * 33 + nq * 4 + 3];
        float4 w4 = *reinterpret_cast<const float4*>(W2 + (size_t)f * K_DIM + kq * 4);
        acc[0][0] += a0 * w4.x; acc[0][1] += a0 * w4.y; acc[0][2] += a0 * w4.z; acc[0][3] += a0 * w4.w;
        acc[1][0] += a1 * w4.x; acc[1][1] += a1 * w4.y; acc[1][2] += a1 * w4.z; acc[1][3] += a1 * w4.w;
        acc[2][0] += a2 * w4.x; acc[2][1] += a2 * w4.y; acc[2][2] += a2 * w4.z; acc[2][3] += a2 * w4.w;
        acc[3][0] += a3 * w4.x; acc[3][1] += a3 * w4.y; acc[3][2] += a3 * w4.z; acc[3][3] += a3 * w4.w;
    }
    int head = kq >> 3;
    float4 va = *reinterpret_cast<const float4*>(asf + kq * 4);
    float4 vd = *reinterpret_cast<const float4*>(adf + kq * 4);
    float4 vg = *reinterpret_cast<const float4*>(linw + kq * 4);
#pragma unroll
    for (int i = 0; i < 4; ++i) {
        int n = n0 + nq * 4 + i;
        float s = acc[i][0] * va.x + acc[i][1] * va.y + acc[i][2] * va.z + acc[i][3] * va.w;
        float d = acc[i][0] * vd.x + acc[i][1] * vd.y + acc[i][2] * vd.z + acc[i][3] * vd.w;
        float g = acc[i][0] * vg.x + acc[i][1] * vg.y + acc[i][2] * vg.z + acc[i][3] * vg.w;
#pragma unroll
        for (int m = 1; m < 8; m <<= 1) {
            s += __shfl_xor(s, m, 8);
            d += __shfl_xor(d, m, 8);
            g += __shfl_xor(g, m, 8);
        }
        if ((kq & 7) == 0 && n < N_NODES) {
            asg[(size_t)n * 8 + head] = s;
            asg[(size_t)n * 8 + 4 + head] = g;
            adn[(size_t)n * 4 + head] = d;
        }
    }
}

// ---------------------------------------------------------------------------
// K7: layer-2 gather: 16-lane group per node, lanes stride the edge list.
// ---------------------------------------------------------------------------
__global__ void __launch_bounds__(256)
k7_l2(const int* __restrict__ starts, const int* __restrict__ el_src,
      const float4* __restrict__ el_ae2, const float* __restrict__ asg,
      const float* __restrict__ adn, const float* __restrict__ cbias,
      float* __restrict__ out) {
    int t = threadIdx.x;
    int g16 = t & 15;
    int node = blockIdx.x * 16 + (t >> 4);
    if (node >= N_NODES) return;
    int s = starts[node], e = starts[node + 1];
    float4 ad4 = *reinterpret_cast<const float4*>(adn + (size_t)node * 4);
    float4 dsum = make_float4(0, 0, 0, 0);
    float4 gsum = make_float4(0, 0, 0, 0);
    float4 aesum = make_float4(0, 0, 0, 0);
    for (int j = s + g16; j < e; j += 16) {
        int src = el_src[j];
        float4 ae4 = el_ae2[j];
        const float* ap = asg + (size_t)src * 8;
        float4 as4 = *reinterpret_cast<const float4*>(ap);
        float4 g4  = *reinterpret_cast<const float4*>(ap + 4);
        float e0 = __expf(lrelu(as4.x + ad4.x + ae4.x));
        float e1 = __expf(lrelu(as4.y + ad4.y + ae4.y));
        float e2 = __expf(lrelu(as4.z + ad4.z + ae4.z));
        float e3 = __expf(lrelu(as4.w + ad4.w + ae4.w));
        dsum.x += e0; dsum.y += e1; dsum.z += e2; dsum.w += e3;
        gsum.x += e0 * g4.x; gsum.y += e1 * g4.y; gsum.z += e2 * g4.z; gsum.w += e3 * g4.w;
        aesum.x += ae4.x; aesum.y += ae4.y; aesum.z += ae4.z; aesum.w += ae4.w;
    }
#pragma unroll
    for (int m = 1; m < 16; m <<= 1) {
        dsum.x += __shfl_xor(dsum.x, m, 16);  dsum.y += __shfl_xor(dsum.y, m, 16);
        dsum.z += __shfl_xor(dsum.z, m, 16);  dsum.w += __shfl_xor(dsum.w, m, 16);
        gsum.x += __shfl_xor(gsum.x, m, 16);  gsum.y += __shfl_xor(gsum.y, m, 16);
        gsum.z += __shfl_xor(gsum.z, m, 16);  gsum.w += __shfl_xor(gsum.w, m, 16);
        aesum.x += __shfl_xor(aesum.x, m, 16); aesum.y += __shfl_xor(aesum.y, m, 16);
        aesum.z += __shfl_xor(aesum.z, m, 16); aesum.w += __shfl_xor(aesum.w, m, 16);
    }
    if (g16 == 0) {
        float deg = fmaxf((float)(e - s), 1.f);
        const float* ap = asg + (size_t)node * 8;
        float4 mas = *reinterpret_cast<const float4*>(ap);
        float4 mg  = *reinterpret_cast<const float4*>(ap + 4);
        float r = cbias[0];
        float e0;
        e0 = __expf(lrelu(mas.x + ad4.x + aesum.x / deg)); r += (gsum.x + e0 * mg.x) / (dsum.x + e0);
        e0 = __expf(lrelu(mas.y + ad4.y + aesum.y / deg)); r += (gsum.y + e0 * mg.y) / (dsum.y + e0);
        e0 = __expf(lrelu(mas.z + ad4.z + aesum.z / deg)); r += (gsum.z + e0 * mg.z) / (dsum.z + e0);
        e0 = __expf(lrelu(mas.w + ad4.w + aesum.w / deg)); r += (gsum.w + e0 * mg.w) / (dsum.w + e0);
        out[node] = r;
    }
}

// ---------------------------------------------------------------------------
extern "C" void kernel_launch(void* const* d_in, const int* in_sizes, int n_in,
                              void* d_out, int out_size, void* d_ws, size_t ws_size,
                              hipStream_t stream) {
    (void)in_sizes; (void)n_in; (void)out_size;
    const float* x    = (const float*)d_in[0];
    const float* ea   = (const float*)d_in[1];
    const float* W1   = (const float*)d_in[2];
    const float* as1  = (const float*)d_in[3];
    const float* ad1  = (const float*)d_in[4];
    const float* We1  = (const float*)d_in[5];
    const float* ae1  = (const float*)d_in[6];
    const float* b1   = (const float*)d_in[7];
    const float* W2   = (const float*)d_in[8];
    const float* as2  = (const float*)d_in[9];
    const float* ad2  = (const float*)d_in[10];
    const float* We2  = (const float*)d_in[11];
    const float* ae2  = (const float*)d_in[12];
    const float* b2   = (const float*)d_in[13];
    const float* linw = (const float*)d_in[14];
    const float* linb = (const float*)d_in[15];
    const int*   ei   = (const int*)d_in[16];
    float* out = (float*)d_out;
    float* ws  = (float*)d_ws;

    size_t off = 0;
    float* h1p   = ws + off; off += (size_t)N_NODES * K_DIM;
    float* x2    = ws + off; off += (size_t)N_NODES * K_DIM;
    float* asn1  = ws + off; off += (size_t)N_NODES * 4;
    float* adn1  = ws + off; off += (size_t)N_NODES * 4;
    float* asg2  = ws + off; off += (size_t)N_NODES * 8;
    float* adn2  = ws + off; off += (size_t)N_NODES * 4;
    float* vbuf  = ws + off; off += 512;
    float* cbias = ws + off; off += 64;
    int* starts  = (int*)(ws + off); off += (size_t)N_NODES + 8;
    int* cursor  = (int*)(ws + off); off += (size_t)N_NODES;
    int* el_src  = (int*)(ws + off); off += (size_t)N_EDGES;
    float* elae1 = ws + off; off += (size_t)N_EDGES * 4;
    float* elae2 = ws + off; off += (size_t)N_EDGES * 4;
    int* cnt     = (int*)(ws + off); off += (size_t)N_NODES;

    if (ws_size < off * sizeof(float)) return; // workspace too small: fail visibly

    hipMemsetAsync(cnt, 0, N_NODES * sizeof(int), stream);

    k0_fold<<<1, 256, 0, stream>>>(We1, ae1, We2, ae2, b2, linw, linb, vbuf, cbias);
    kc_count<<<(N_EDGES + 255) / 256, 256, 0, stream>>>(ei, cnt);
    k2_scan<<<1, 1024, 0, stream>>>(cnt, starts, cursor);
    k1_edge<<<N_EDGES / 256, 256, 0, stream>>>(ea, ei, vbuf, cursor, el_src,
                                               (float4*)elae1, (float4*)elae2);
    k4_proj1<<<(N_NODES + 31) / 32, 256, 0, stream>>>(x, W1, as1, ad1, h1p, asn1, adn1);
    k5_agg1<<<(N_NODES + 3) / 4, 256, 0, stream>>>(starts, el_src, elae1,
                                                   asn1, adn1, h1p, b1, x2);
    k6_proj2<<<(N_NODES + 31) / 32, 256, 0, stream>>>(x2, W2, as2, ad2, linw, asg2, adn2);
    k7_l2<<<(N_NODES + 15) / 16, 256, 0, stream>>>(starts, el_src, (const float4*)elae2,
                                                   asg2, adn2, cbias, out);
}

// Round 6
// 390.204 us; speedup vs baseline: 2.2624x; 1.0135x over previous
//
#include <hip/hip_runtime.h>

#define N_NODES 50000
#define N_EDGES 800000
#define F_IN    64
#define HEADS   4
#define CH      32
#define K_DIM   128
#define NEG     0.2f

__device__ __forceinline__ float lrelu(float x) { return x > 0.f ? x : NEG * x; }

// ---------------------------------------------------------------------------
// K0: fold We*ae -> v[o][f] (o=0..3 layer1 heads, 4..7 layer2 heads), and
//     cbias = dot(b2, lin_w) + lin_b
// ---------------------------------------------------------------------------
__global__ void k0_fold(const float* __restrict__ We1, const float* __restrict__ ae1,
                        const float* __restrict__ We2, const float* __restrict__ ae2,
                        const float* __restrict__ b2,  const float* __restrict__ linw,
                        const float* __restrict__ linb,
                        float* __restrict__ v, float* __restrict__ cbias) {
    int t = threadIdx.x; // 256 threads
    for (int idx = t; idx < 512; idx += 256) {
        int o = idx >> 6, f = idx & 63;
        const float* We = (o < 4) ? We1 : We2;
        const float* ae = (o < 4) ? ae1 : ae2;
        int h = o & 3;
        float s = 0.f;
        for (int c = 0; c < CH; ++c)
            s += We[f * K_DIM + h * CH + c] * ae[h * CH + c];
        v[o * 64 + f] = s;
    }
    if (t == 0) {
        float s = 0.f;
        for (int k = 0; k < K_DIM; ++k) s += b2[k] * linw[k];
        *cbias = s + linb[0];
    }
}

// ---------------------------------------------------------------------------
// Kc: degree count from ei only.
// ---------------------------------------------------------------------------
__global__ void __launch_bounds__(256)
kc_count(const int* __restrict__ ei, int* __restrict__ cnt) {
    int e = blockIdx.x * 256 + threadIdx.x;
    if (e >= N_EDGES) return;
    atomicAdd(cnt + ei[N_EDGES + e], 1);
}

// ---------------------------------------------------------------------------
// K2: exclusive prefix scan of cnt -> starts[N+1], cursor. Single block,
//     shuffle-based.
// ---------------------------------------------------------------------------
__global__ void __launch_bounds__(1024)
k2_scan(const int* __restrict__ cnt, int* __restrict__ starts, int* __restrict__ cursor) {
    __shared__ int wsum[16];
    __shared__ int s_carry;
    int t = threadIdx.x;
    int lane = t & 63, wid = t >> 6;
    if (t == 0) s_carry = 0;
    __syncthreads();
    for (int base = 0; base < N_NODES; base += 1024) {
        int i = base + t;
        int v = (i < N_NODES) ? cnt[i] : 0;
        int sc = v; // inclusive wave scan
#pragma unroll
        for (int s = 1; s < 64; s <<= 1) {
            int u = __shfl_up(sc, s, 64);
            if (lane >= s) sc += u;
        }
        if (lane == 63) wsum[wid] = sc;
        __syncthreads();
        if (wid == 0 && lane < 16) {
            int ws = wsum[lane];
#pragma unroll
            for (int s = 1; s < 16; s <<= 1) {
                int u = __shfl_up(ws, s, 64);
                if (lane >= s) ws += u;
            }
            wsum[lane] = ws;
        }
        __syncthreads();
        int carry = s_carry;
        int woff = (wid == 0) ? 0 : wsum[wid - 1];
        int excl = carry + woff + sc - v;
        if (i < N_NODES) { starts[i] = excl; cursor[i] = excl; }
        __syncthreads();
        if (t == 0) s_carry = carry + wsum[15];
    }
    __syncthreads();
    if (t == 0) starts[N_NODES] = s_carry;
}

// ---------------------------------------------------------------------------
// K1: per-edge a_e, thread-per-edge, TWO-PHASE: (a) stage the full 64-float
//     row into r[16] float4 registers (16 loads in flight -> MLP-bound fix,
//     R5 lesson: unroll-4 capped BW at 2 TB/s), (b) 512 FMAs against
//     LDS-broadcast v. One edge/thread keeps VGPR ~100 (R4 lesson: 2-edge
//     full unroll spilled at 256 VGPR).
// ---------------------------------------------------------------------------
__global__ void __launch_bounds__(256)
k1_edge(const float* __restrict__ ea, const int* __restrict__ ei,
        const float* __restrict__ v, int* __restrict__ cursor,
        int* __restrict__ el_src, float4* __restrict__ el_ae1,
        float4* __restrict__ el_ae2) {
    __shared__ float sv[512];
    int t = threadIdx.x;
    sv[t] = v[t];
    sv[t + 256] = v[t + 256];
    __syncthreads();
    int eid = blockIdx.x * 256 + t;
    const float* row = ea + (size_t)eid * F_IN;
    float4 r[16];
#pragma unroll
    for (int c = 0; c < 16; ++c)
        r[c] = *reinterpret_cast<const float4*>(row + c * 4);
    float acc[8] = {0, 0, 0, 0, 0, 0, 0, 0};
#pragma unroll
    for (int c = 0; c < 16; ++c) {
        float4 x4 = r[c];
#pragma unroll
        for (int o = 0; o < 8; ++o) {
            float4 vv = *reinterpret_cast<const float4*>(sv + o * 64 + c * 4);
            acc[o] = fmaf(x4.x, vv.x, fmaf(x4.y, vv.y, fmaf(x4.z, vv.z, fmaf(x4.w, vv.w, acc[o]))));
        }
    }
    int dst = ei[N_EDGES + eid];
    int src = ei[eid];
    int pos = atomicAdd(cursor + dst, 1);
    el_src[pos] = src;
    el_ae1[pos] = make_float4(acc[0], acc[1], acc[2], acc[3]);
    el_ae2[pos] = make_float4(acc[4], acc[5], acc[6], acc[7]);
}

// ---------------------------------------------------------------------------
// K4: layer-1 node projection, register-tiled 4 nodes x 4 cols per thread.
// ---------------------------------------------------------------------------
__global__ void __launch_bounds__(256)
k4_proj1(const float* __restrict__ x, const float* __restrict__ W,
         const float* __restrict__ asf, const float* __restrict__ adf,
         float* __restrict__ hp, float* __restrict__ asn, float* __restrict__ adn) {
    __shared__ float sxT[F_IN * 33]; // [f][i], i in [0,32), pad 1
    int t = threadIdx.x;
    int n0 = blockIdx.x * 32;
    {
        int f = t & 63, i0 = t >> 6;
#pragma unroll
        for (int s = 0; s < 8; ++s) {
            int i = i0 + s * 4;
            int n = n0 + i;
            sxT[f * 33 + i] = (n < N_NODES) ? x[(size_t)n * F_IN + f] : 0.f;
        }
    }
    __syncthreads();
    int kq = t & 31, nq = t >> 5;
    float acc[4][4] = {};
    for (int f = 0; f < F_IN; ++f) {
        float a0 = sxT[f * 33 + nq * 4 + 0];
        float a1 = sxT[f * 33 + nq * 4 + 1];
        float a2 = sxT[f * 33 + nq * 4 + 2];
        float a3 = sxT[f * 33 + nq * 4 + 3];
        float4 w4 = *reinterpret_cast<const float4*>(W + (size_t)f * K_DIM + kq * 4);
        acc[0][0] += a0 * w4.x; acc[0][1] += a0 * w4.y; acc[0][2] += a0 * w4.z; acc[0][3] += a0 * w4.w;
        acc[1][0] += a1 * w4.x; acc[1][1] += a1 * w4.y; acc[1][2] += a1 * w4.z; acc[1][3] += a1 * w4.w;
        acc[2][0] += a2 * w4.x; acc[2][1] += a2 * w4.y; acc[2][2] += a2 * w4.z; acc[2][3] += a2 * w4.w;
        acc[3][0] += a3 * w4.x; acc[3][1] += a3 * w4.y; acc[3][2] += a3 * w4.z; acc[3][3] += a3 * w4.w;
    }
    int head = kq >> 3;
    float4 va = *reinterpret_cast<const float4*>(asf + kq * 4);
    float4 vd = *reinterpret_cast<const float4*>(adf + kq * 4);
#pragma unroll
    for (int i = 0; i < 4; ++i) {
        int n = n0 + nq * 4 + i;
        if (n < N_NODES)
            *reinterpret_cast<float4*>(hp + (size_t)n * K_DIM + kq * 4) =
                make_float4(acc[i][0], acc[i][1], acc[i][2], acc[i][3]);
        float s = acc[i][0] * va.x + acc[i][1] * va.y + acc[i][2] * va.z + acc[i][3] * va.w;
        float d = acc[i][0] * vd.x + acc[i][1] * vd.y + acc[i][2] * vd.z + acc[i][3] * vd.w;
#pragma unroll
        for (int m = 1; m < 8; m <<= 1) {
            s += __shfl_xor(s, m, 8);
            d += __shfl_xor(d, m, 8);
        }
        if ((kq & 7) == 0 && n < N_NODES) {
            asn[(size_t)n * 4 + head] = s;
            adn[(size_t)n * 4 + head] = d;
        }
    }
}

// ---------------------------------------------------------------------------
// K5: layer-1 gather aggregation. One 64-lane wave per node; lane owns 2
//     output columns. No atomics.
// ---------------------------------------------------------------------------
__global__ void __launch_bounds__(256)
k5_agg1(const int* __restrict__ starts, const int* __restrict__ el_src,
        const float* __restrict__ el_ae1,
        const float* __restrict__ asn, const float* __restrict__ adn,
        const float* __restrict__ hp, const float* __restrict__ b1,
        float* __restrict__ x2) {
    int t = threadIdx.x;
    int lane = t & 63;
    int node = blockIdx.x * 4 + (t >> 6);
    if (node >= N_NODES) return;
    int s = starts[node], e = starts[node + 1];
    int head = lane >> 4; // col pair = lane*2; head = (lane*2)>>5
    float adv = adn[(size_t)node * 4 + head];
    float accx = 0.f, accy = 0.f, dsum = 0.f, aesum = 0.f;
    for (int j = s; j < e; ++j) {
        int src = el_src[j];
        float ae = el_ae1[(size_t)j * 4 + head];
        float av = asn[(size_t)src * 4 + head];
        float ex = __expf(lrelu(av + adv + ae));
        float2 hv = *reinterpret_cast<const float2*>(hp + (size_t)src * K_DIM + lane * 2);
        accx += ex * hv.x;
        accy += ex * hv.y;
        dsum += ex;
        aesum += ae;
    }
    float deg = (float)(e - s);
    float al = aesum / fmaxf(deg, 1.f); // self-loop a_e = mean of incoming
    float exl = __expf(lrelu(asn[(size_t)node * 4 + head] + adv + al));
    float2 hv = *reinterpret_cast<const float2*>(hp + (size_t)node * K_DIM + lane * 2);
    accx += exl * hv.x;
    accy += exl * hv.y;
    dsum += exl;
    float2 bb = *reinterpret_cast<const float2*>(b1 + lane * 2);
    float2 o;
    o.x = fmaxf(accx / dsum + bb.x, 0.f);
    o.y = fmaxf(accy / dsum + bb.y, 0.f);
    *reinterpret_cast<float2*>(x2 + (size_t)node * K_DIM + lane * 2) = o;
}

// ---------------------------------------------------------------------------
// K6: layer-2 node projection, register-tiled like K4 (F=128). Outputs packed
//     asg[n] = {a_s2[4], g[4]} + adn2. h2p never materialized.
// ---------------------------------------------------------------------------
__global__ void __launch_bounds__(256)
k6_proj2(const float* __restrict__ x2, const float* __restrict__ W2,
         const float* __restrict__ asf, const float* __restrict__ adf,
         const float* __restrict__ linw,
         float* __restrict__ asg, float* __restrict__ adn) {
    __shared__ float sxT[K_DIM * 33]; // [f][i], i in [0,32), pad 1
    int t = threadIdx.x;
    int n0 = blockIdx.x * 32;
    {
        int f = t & 127, i0 = t >> 7;
#pragma unroll
        for (int s = 0; s < 16; ++s) {
            int i = i0 + s * 2;
            int n = n0 + i;
            sxT[f * 33 + i] = (n < N_NODES) ? x2[(size_t)n * K_DIM + f] : 0.f;
        }
    }
    __syncthreads();
    int kq = t & 31, nq = t >> 5;
    float acc[4][4] = {};
    for (int f = 0; f < K_DIM; ++f) {
        float a0 = sxT[f * 33 + nq * 4 + 0];
        float a1 = sxT[f * 33 + nq * 4 + 1];
        float a2 = sxT[f * 33 + nq * 4 + 2];
        float a3 = sxT[f * 33 + nq * 4 + 3];
        float4 w4 = *reinterpret_cast<const float4*>(W2 + (size_t)f * K_DIM + kq * 4);
        acc[0][0] += a0 * w4.x; acc[0][1] += a0 * w4.y; acc[0][2] += a0 * w4.z; acc[0][3] += a0 * w4.w;
        acc[1][0] += a1 * w4.x; acc[1][1] += a1 * w4.y; acc[1][2] += a1 * w4.z; acc[1][3] += a1 * w4.w;
        acc[2][0] += a2 * w4.x; acc[2][1] += a2 * w4.y; acc[2][2] += a2 * w4.z; acc[2][3] += a2 * w4.w;
        acc[3][0] += a3 * w4.x; acc[3][1] += a3 * w4.y; acc[3][2] += a3 * w4.z; acc[3][3] += a3 * w4.w;
    }
    int head = kq >> 3;
    float4 va = *reinterpret_cast<const float4*>(asf + kq * 4);
    float4 vd = *reinterpret_cast<const float4*>(adf + kq * 4);
    float4 vg = *reinterpret_cast<const float4*>(linw + kq * 4);
#pragma unroll
    for (int i = 0; i < 4; ++i) {
        int n = n0 + nq * 4 + i;
        float s = acc[i][0] * va.x + acc[i][1] * va.y + acc[i][2] * va.z + acc[i][3] * va.w;
        float d = acc[i][0] * vd.x + acc[i][1] * vd.y + acc[i][2] * vd.z + acc[i][3] * vd.w;
        float g = acc[i][0] * vg.x + acc[i][1] * vg.y + acc[i][2] * vg.z + acc[i][3] * vg.w;
#pragma unroll
        for (int m = 1; m < 8; m <<= 1) {
            s += __shfl_xor(s, m, 8);
            d += __shfl_xor(d, m, 8);
            g += __shfl_xor(g, m, 8);
        }
        if ((kq & 7) == 0 && n < N_NODES) {
            asg[(size_t)n * 8 + head] = s;
            asg[(size_t)n * 8 + 4 + head] = g;
            adn[(size_t)n * 4 + head] = d;
        }
    }
}

// ---------------------------------------------------------------------------
// K7: layer-2 gather: 16-lane group per node, lanes stride the edge list.
// ---------------------------------------------------------------------------
__global__ void __launch_bounds__(256)
k7_l2(const int* __restrict__ starts, const int* __restrict__ el_src,
      const float4* __restrict__ el_ae2, const float* __restrict__ asg,
      const float* __restrict__ adn, const float* __restrict__ cbias,
      float* __restrict__ out) {
    int t = threadIdx.x;
    int g16 = t & 15;
    int node = blockIdx.x * 16 + (t >> 4);
    if (node >= N_NODES) return;
    int s = starts[node], e = starts[node + 1];
    float4 ad4 = *reinterpret_cast<const float4*>(adn + (size_t)node * 4);
    float4 dsum = make_float4(0, 0, 0, 0);
    float4 gsum = make_float4(0, 0, 0, 0);
    float4 aesum = make_float4(0, 0, 0, 0);
    for (int j = s + g16; j < e; j += 16) {
        int src = el_src[j];
        float4 ae4 = el_ae2[j];
        const float* ap = asg + (size_t)src * 8;
        float4 as4 = *reinterpret_cast<const float4*>(ap);
        float4 g4  = *reinterpret_cast<const float4*>(ap + 4);
        float e0 = __expf(lrelu(as4.x + ad4.x + ae4.x));
        float e1 = __expf(lrelu(as4.y + ad4.y + ae4.y));
        float e2 = __expf(lrelu(as4.z + ad4.z + ae4.z));
        float e3 = __expf(lrelu(as4.w + ad4.w + ae4.w));
        dsum.x += e0; dsum.y += e1; dsum.z += e2; dsum.w += e3;
        gsum.x += e0 * g4.x; gsum.y += e1 * g4.y; gsum.z += e2 * g4.z; gsum.w += e3 * g4.w;
        aesum.x += ae4.x; aesum.y += ae4.y; aesum.z += ae4.z; aesum.w += ae4.w;
    }
#pragma unroll
    for (int m = 1; m < 16; m <<= 1) {
        dsum.x += __shfl_xor(dsum.x, m, 16);  dsum.y += __shfl_xor(dsum.y, m, 16);
        dsum.z += __shfl_xor(dsum.z, m, 16);  dsum.w += __shfl_xor(dsum.w, m, 16);
        gsum.x += __shfl_xor(gsum.x, m, 16);  gsum.y += __shfl_xor(gsum.y, m, 16);
        gsum.z += __shfl_xor(gsum.z, m, 16);  gsum.w += __shfl_xor(gsum.w, m, 16);
        aesum.x += __shfl_xor(aesum.x, m, 16); aesum.y += __shfl_xor(aesum.y, m, 16);
        aesum.z += __shfl_xor(aesum.z, m, 16); aesum.w += __shfl_xor(aesum.w, m, 16);
    }
    if (g16 == 0) {
        float deg = fmaxf((float)(e - s), 1.f);
        const float* ap = asg + (size_t)node * 8;
        float4 mas = *reinterpret_cast<const float4*>(ap);
        float4 mg  = *reinterpret_cast<const float4*>(ap + 4);
        float r = cbias[0];
        float e0;
        e0 = __expf(lrelu(mas.x + ad4.x + aesum.x / deg)); r += (gsum.x + e0 * mg.x) / (dsum.x + e0);
        e0 = __expf(lrelu(mas.y + ad4.y + aesum.y / deg)); r += (gsum.y + e0 * mg.y) / (dsum.y + e0);
        e0 = __expf(lrelu(mas.z + ad4.z + aesum.z / deg)); r += (gsum.z + e0 * mg.z) / (dsum.z + e0);
        e0 = __expf(lrelu(mas.w + ad4.w + aesum.w / deg)); r += (gsum.w + e0 * mg.w) / (dsum.w + e0);
        out[node] = r;
    }
}

// ---------------------------------------------------------------------------
extern "C" void kernel_launch(void* const* d_in, const int* in_sizes, int n_in,
                              void* d_out, int out_size, void* d_ws, size_t ws_size,
                              hipStream_t stream) {
    (void)in_sizes; (void)n_in; (void)out_size;
    const float* x    = (const float*)d_in[0];
    const float* ea   = (const float*)d_in[1];
    const float* W1   = (const float*)d_in[2];
    const float* as1  = (const float*)d_in[3];
    const float* ad1  = (const float*)d_in[4];
    const float* We1  = (const float*)d_in[5];
    const float* ae1  = (const float*)d_in[6];
    const float* b1   = (const float*)d_in[7];
    const float* W2   = (const float*)d_in[8];
    const float* as2  = (const float*)d_in[9];
    const float* ad2  = (const float*)d_in[10];
    const float* We2  = (const float*)d_in[11];
    const float* ae2  = (const float*)d_in[12];
    const float* b2   = (const float*)d_in[13];
    const float* linw = (const float*)d_in[14];
    const float* linb = (const float*)d_in[15];
    const int*   ei   = (const int*)d_in[16];
    float* out = (float*)d_out;
    float* ws  = (float*)d_ws;

    size_t off = 0;
    float* h1p   = ws + off; off += (size_t)N_NODES * K_DIM;
    float* x2    = ws + off; off += (size_t)N_NODES * K_DIM;
    float* asn1  = ws + off; off += (size_t)N_NODES * 4;
    float* adn1  = ws + off; off += (size_t)N_NODES * 4;
    float* asg2  = ws + off; off += (size_t)N_NODES * 8;
    float* adn2  = ws + off; off += (size_t)N_NODES * 4;
    float* vbuf  = ws + off; off += 512;
    float* cbias = ws + off; off += 64;
    int* starts  = (int*)(ws + off); off += (size_t)N_NODES + 8;
    int* cursor  = (int*)(ws + off); off += (size_t)N_NODES;
    int* el_src  = (int*)(ws + off); off += (size_t)N_EDGES;
    float* elae1 = ws + off; off += (size_t)N_EDGES * 4;
    float* elae2 = ws + off; off += (size_t)N_EDGES * 4;
    int* cnt     = (int*)(ws + off); off += (size_t)N_NODES;

    if (ws_size < off * sizeof(float)) return; // workspace too small: fail visibly

    hipMemsetAsync(cnt, 0, N_NODES * sizeof(int), stream);

    k0_fold<<<1, 256, 0, stream>>>(We1, ae1, We2, ae2, b2, linw, linb, vbuf, cbias);
    kc_count<<<(N_EDGES + 255) / 256, 256, 0, stream>>>(ei, cnt);
    k2_scan<<<1, 1024, 0, stream>>>(cnt, starts, cursor);
    k1_edge<<<N_EDGES / 256, 256, 0, stream>>>(ea, ei, vbuf, cursor, el_src,
                                               (float4*)elae1, (float4*)elae2);
    k4_proj1<<<(N_NODES + 31) / 32, 256, 0, stream>>>(x, W1, as1, ad1, h1p, asn1, adn1);
    k5_agg1<<<(N_NODES + 3) / 4, 256, 0, stream>>>(starts, el_src, elae1,
                                                   asn1, adn1, h1p, b1, x2);
    k6_proj2<<<(N_NODES + 31) / 32, 256, 0, stream>>>(x2, W2, as2, ad2, linw, asg2, adn2);
    k7_l2<<<(N_NODES + 15) / 16, 256, 0, stream>>>(starts, el_src, (const float4*)elae2,
                                                   asg2, adn2, cbias, out);
}

// Round 7
// 383.193 us; speedup vs baseline: 2.3038x; 1.0183x over previous
//
#include <hip/hip_runtime.h>

#define N_NODES 50000
#define N_EDGES 800000
#define F_IN    64
#define HEADS   4
#define CH      32
#define K_DIM   128
#define NEG     0.2f

__device__ __forceinline__ float lrelu(float x) { return x > 0.f ? x : NEG * x; }

// ---------------------------------------------------------------------------
// K0: fold We*ae -> v[o][f] (o=0..3 layer1 heads, 4..7 layer2 heads), and
//     cbias = dot(b2, lin_w) + lin_b
// ---------------------------------------------------------------------------
__global__ void k0_fold(const float* __restrict__ We1, const float* __restrict__ ae1,
                        const float* __restrict__ We2, const float* __restrict__ ae2,
                        const float* __restrict__ b2,  const float* __restrict__ linw,
                        const float* __restrict__ linb,
                        float* __restrict__ v, float* __restrict__ cbias) {
    int t = threadIdx.x; // 256 threads
    for (int idx = t; idx < 512; idx += 256) {
        int o = idx >> 6, f = idx & 63;
        const float* We = (o < 4) ? We1 : We2;
        const float* ae = (o < 4) ? ae1 : ae2;
        int h = o & 3;
        float s = 0.f;
        for (int c = 0; c < CH; ++c)
            s += We[f * K_DIM + h * CH + c] * ae[h * CH + c];
        v[o * 64 + f] = s;
    }
    if (t == 0) {
        float s = 0.f;
        for (int k = 0; k < K_DIM; ++k) s += b2[k] * linw[k];
        *cbias = s + linb[0];
    }
}

// ---------------------------------------------------------------------------
// Kc: degree count from ei only.
// ---------------------------------------------------------------------------
__global__ void __launch_bounds__(256)
kc_count(const int* __restrict__ ei, int* __restrict__ cnt) {
    int e = blockIdx.x * 256 + threadIdx.x;
    if (e >= N_EDGES) return;
    atomicAdd(cnt + ei[N_EDGES + e], 1);
}

// ---------------------------------------------------------------------------
// K2: exclusive prefix scan of cnt -> starts[N+1], cursor. Single block,
//     shuffle-based.
// ---------------------------------------------------------------------------
__global__ void __launch_bounds__(1024)
k2_scan(const int* __restrict__ cnt, int* __restrict__ starts, int* __restrict__ cursor) {
    __shared__ int wsum[16];
    __shared__ int s_carry;
    int t = threadIdx.x;
    int lane = t & 63, wid = t >> 6;
    if (t == 0) s_carry = 0;
    __syncthreads();
    for (int base = 0; base < N_NODES; base += 1024) {
        int i = base + t;
        int v = (i < N_NODES) ? cnt[i] : 0;
        int sc = v; // inclusive wave scan
#pragma unroll
        for (int s = 1; s < 64; s <<= 1) {
            int u = __shfl_up(sc, s, 64);
            if (lane >= s) sc += u;
        }
        if (lane == 63) wsum[wid] = sc;
        __syncthreads();
        if (wid == 0 && lane < 16) {
            int ws = wsum[lane];
#pragma unroll
            for (int s = 1; s < 16; s <<= 1) {
                int u = __shfl_up(ws, s, 64);
                if (lane >= s) ws += u;
            }
            wsum[lane] = ws;
        }
        __syncthreads();
        int carry = s_carry;
        int woff = (wid == 0) ? 0 : wsum[wid - 1];
        int excl = carry + woff + sc - v;
        if (i < N_NODES) { starts[i] = excl; cursor[i] = excl; }
        __syncthreads();
        if (t == 0) s_carry = carry + wsum[15];
    }
    __syncthreads();
    if (t == 0) starts[N_NODES] = s_carry;
}

// ---------------------------------------------------------------------------
// K1: per-edge a_e. R6 lesson: per-thread-row global loads are UNCOALESCED
//     (lane stride 256 B -> 64 lines/instr, VMEM line-request bound at ~145us
//     regardless of ILP). Fix: coalesced staging of 32-edge tiles into LDS
//     (double-buffered, stride 68 dwords = 16B-aligned + conflict-free reads),
//     thread = (edge, output) with v-row in 16 float4 regs -> zero shuffles,
//     zero v-table LDS reads. 8 tiles/block, 1 barrier/tile.
// ---------------------------------------------------------------------------
__global__ void __launch_bounds__(256)
k1_edge(const float* __restrict__ ea, const int* __restrict__ ei,
        const float* __restrict__ v, int* __restrict__ cursor,
        int* __restrict__ el_src, float4* __restrict__ el_ae1,
        float4* __restrict__ el_ae2) {
    __shared__ float sx[2][32 * 68];
    int t = threadIdx.x;
    int o  = t & 7;   // output index (0..3: layer1 heads, 4..7: layer2 heads)
    int le = t >> 3;  // local edge within tile (0..31)
    float4 vr[16];
    {
        const float4* vrow = reinterpret_cast<const float4*>(v + o * 64);
#pragma unroll
        for (int c = 0; c < 16; ++c) vr[c] = vrow[c];
    }
    const float4* ea4 = reinterpret_cast<const float4*>(ea);
    int base = blockIdx.x * 256; // 8 tiles * 32 edges
    {
        size_t gb = (size_t)base * 16;
        float4 a = ea4[gb + t];
        float4 b = ea4[gb + t + 256];
        int g0 = t, g1 = t + 256;
        *reinterpret_cast<float4*>(&sx[0][(g0 >> 4) * 68 + (g0 & 15) * 4]) = a;
        *reinterpret_cast<float4*>(&sx[0][(g1 >> 4) * 68 + (g1 & 15) * 4]) = b;
    }
    __syncthreads();
    for (int tile = 0; tile < 8; ++tile) {
        float4 a, b;
        if (tile < 7) { // prefetch next tile (coalesced)
            size_t gb = (size_t)(base + (tile + 1) * 32) * 16;
            a = ea4[gb + t];
            b = ea4[gb + t + 256];
        }
        const float* row = &sx[tile & 1][le * 68];
        float4 ac = make_float4(0.f, 0.f, 0.f, 0.f);
#pragma unroll
        for (int c = 0; c < 16; ++c) {
            float4 x4 = *reinterpret_cast<const float4*>(row + c * 4);
            ac.x = fmaf(x4.x, vr[c].x, ac.x);
            ac.y = fmaf(x4.y, vr[c].y, ac.y);
            ac.z = fmaf(x4.z, vr[c].z, ac.z);
            ac.w = fmaf(x4.w, vr[c].w, ac.w);
        }
        float acc = (ac.x + ac.y) + (ac.z + ac.w);
        int eid = base + tile * 32 + le;
        int pos;
        if (o == 0) {
            int dst = ei[N_EDGES + eid];
            pos = atomicAdd(cursor + dst, 1);
            el_src[pos] = ei[eid];
        }
        pos = __shfl(pos, (t & 63) & ~7, 64); // broadcast from o==0 lane of 8-group
        float* ob = (o < 4) ? reinterpret_cast<float*>(el_ae1)
                            : reinterpret_cast<float*>(el_ae2);
        ob[(size_t)pos * 4 + (o & 3)] = acc;
        if (tile < 7) { // write next tile into other buffer
            int g0 = t, g1 = t + 256;
            int nb = (tile + 1) & 1;
            *reinterpret_cast<float4*>(&sx[nb][(g0 >> 4) * 68 + (g0 & 15) * 4]) = a;
            *reinterpret_cast<float4*>(&sx[nb][(g1 >> 4) * 68 + (g1 & 15) * 4]) = b;
        }
        __syncthreads();
    }
}

// ---------------------------------------------------------------------------
// K4: layer-1 node projection, register-tiled 4 nodes x 4 cols per thread.
// ---------------------------------------------------------------------------
__global__ void __launch_bounds__(256)
k4_proj1(const float* __restrict__ x, const float* __restrict__ W,
         const float* __restrict__ asf, const float* __restrict__ adf,
         float* __restrict__ hp, float* __restrict__ asn, float* __restrict__ adn) {
    __shared__ float sxT[F_IN * 33]; // [f][i], i in [0,32), pad 1
    int t = threadIdx.x;
    int n0 = blockIdx.x * 32;
    {
        int f = t & 63, i0 = t >> 6;
#pragma unroll
        for (int s = 0; s < 8; ++s) {
            int i = i0 + s * 4;
            int n = n0 + i;
            sxT[f * 33 + i] = (n < N_NODES) ? x[(size_t)n * F_IN + f] : 0.f;
        }
    }
    __syncthreads();
    int kq = t & 31, nq = t >> 5;
    float acc[4][4] = {};
    for (int f = 0; f < F_IN; ++f) {
        float a0 = sxT[f * 33 + nq * 4 + 0];
        float a1 = sxT[f * 33 + nq * 4 + 1];
        float a2 = sxT[f * 33 + nq * 4 + 2];
        float a3 = sxT[f * 33 + nq * 4 + 3];
        float4 w4 = *reinterpret_cast<const float4*>(W + (size_t)f * K_DIM + kq * 4);
        acc[0][0] += a0 * w4.x; acc[0][1] += a0 * w4.y; acc[0][2] += a0 * w4.z; acc[0][3] += a0 * w4.w;
        acc[1][0] += a1 * w4.x; acc[1][1] += a1 * w4.y; acc[1][2] += a1 * w4.z; acc[1][3] += a1 * w4.w;
        acc[2][0] += a2 * w4.x; acc[2][1] += a2 * w4.y; acc[2][2] += a2 * w4.z; acc[2][3] += a2 * w4.w;
        acc[3][0] += a3 * w4.x; acc[3][1] += a3 * w4.y; acc[3][2] += a3 * w4.z; acc[3][3] += a3 * w4.w;
    }
    int head = kq >> 3;
    float4 va = *reinterpret_cast<const float4*>(asf + kq * 4);
    float4 vd = *reinterpret_cast<const float4*>(adf + kq * 4);
#pragma unroll
    for (int i = 0; i < 4; ++i) {
        int n = n0 + nq * 4 + i;
        if (n < N_NODES)
            *reinterpret_cast<float4*>(hp + (size_t)n * K_DIM + kq * 4) =
                make_float4(acc[i][0], acc[i][1], acc[i][2], acc[i][3]);
        float s = acc[i][0] * va.x + acc[i][1] * va.y + acc[i][2] * va.z + acc[i][3] * va.w;
        float d = acc[i][0] * vd.x + acc[i][1] * vd.y + acc[i][2] * vd.z + acc[i][3] * vd.w;
#pragma unroll
        for (int m = 1; m < 8; m <<= 1) {
            s += __shfl_xor(s, m, 8);
            d += __shfl_xor(d, m, 8);
        }
        if ((kq & 7) == 0 && n < N_NODES) {
            asn[(size_t)n * 4 + head] = s;
            adn[(size_t)n * 4 + head] = d;
        }
    }
}

// ---------------------------------------------------------------------------
// K5: layer-1 gather aggregation. One 64-lane wave per node; lane owns 2
//     output columns. No atomics.
// ---------------------------------------------------------------------------
__global__ void __launch_bounds__(256)
k5_agg1(const int* __restrict__ starts, const int* __restrict__ el_src,
        const float* __restrict__ el_ae1,
        const float* __restrict__ asn, const float* __restrict__ adn,
        const float* __restrict__ hp, const float* __restrict__ b1,
        float* __restrict__ x2) {
    int t = threadIdx.x;
    int lane = t & 63;
    int node = blockIdx.x * 4 + (t >> 6);
    if (node >= N_NODES) return;
    int s = starts[node], e = starts[node + 1];
    int head = lane >> 4; // col pair = lane*2; head = (lane*2)>>5
    float adv = adn[(size_t)node * 4 + head];
    float accx = 0.f, accy = 0.f, dsum = 0.f, aesum = 0.f;
    for (int j = s; j < e; ++j) {
        int src = el_src[j];
        float ae = el_ae1[(size_t)j * 4 + head];
        float av = asn[(size_t)src * 4 + head];
        float ex = __expf(lrelu(av + adv + ae));
        float2 hv = *reinterpret_cast<const float2*>(hp + (size_t)src * K_DIM + lane * 2);
        accx += ex * hv.x;
        accy += ex * hv.y;
        dsum += ex;
        aesum += ae;
    }
    float deg = (float)(e - s);
    float al = aesum / fmaxf(deg, 1.f); // self-loop a_e = mean of incoming
    float exl = __expf(lrelu(asn[(size_t)node * 4 + head] + adv + al));
    float2 hv = *reinterpret_cast<const float2*>(hp + (size_t)node * K_DIM + lane * 2);
    accx += exl * hv.x;
    accy += exl * hv.y;
    dsum += exl;
    float2 bb = *reinterpret_cast<const float2*>(b1 + lane * 2);
    float2 o;
    o.x = fmaxf(accx / dsum + bb.x, 0.f);
    o.y = fmaxf(accy / dsum + bb.y, 0.f);
    *reinterpret_cast<float2*>(x2 + (size_t)node * K_DIM + lane * 2) = o;
}

// ---------------------------------------------------------------------------
// K6: layer-2 node projection, register-tiled like K4 (F=128). Outputs packed
//     asg[n] = {a_s2[4], g[4]} + adn2. h2p never materialized.
// ---------------------------------------------------------------------------
__global__ void __launch_bounds__(256)
k6_proj2(const float* __restrict__ x2, const float* __restrict__ W2,
         const float* __restrict__ asf, const float* __restrict__ adf,
         const float* __restrict__ linw,
         float* __restrict__ asg, float* __restrict__ adn) {
    __shared__ float sxT[K_DIM * 33]; // [f][i], i in [0,32), pad 1
    int t = threadIdx.x;
    int n0 = blockIdx.x * 32;
    {
        int f = t & 127, i0 = t >> 7;
#pragma unroll
        for (int s = 0; s < 16; ++s) {
            int i = i0 + s * 2;
            int n = n0 + i;
            sxT[f * 33 + i] = (n < N_NODES) ? x2[(size_t)n * K_DIM + f] : 0.f;
        }
    }
    __syncthreads();
    int kq = t & 31, nq = t >> 5;
    float acc[4][4] = {};
    for (int f = 0; f < K_DIM; ++f) {
        float a0 = sxT[f * 33 + nq * 4 + 0];
        float a1 = sxT[f * 33 + nq * 4 + 1];
        float a2 = sxT[f * 33 + nq * 4 + 2];
        float a3 = sxT[f * 33 + nq * 4 + 3];
        float4 w4 = *reinterpret_cast<const float4*>(W2 + (size_t)f * K_DIM + kq * 4);
        acc[0][0] += a0 * w4.x; acc[0][1] += a0 * w4.y; acc[0][2] += a0 * w4.z; acc[0][3] += a0 * w4.w;
        acc[1][0] += a1 * w4.x; acc[1][1] += a1 * w4.y; acc[1][2] += a1 * w4.z; acc[1][3] += a1 * w4.w;
        acc[2][0] += a2 * w4.x; acc[2][1] += a2 * w4.y; acc[2][2] += a2 * w4.z; acc[2][3] += a2 * w4.w;
        acc[3][0] += a3 * w4.x; acc[3][1] += a3 * w4.y; acc[3][2] += a3 * w4.z; acc[3][3] += a3 * w4.w;
    }
    int head = kq >> 3;
    float4 va = *reinterpret_cast<const float4*>(asf + kq * 4);
    float4 vd = *reinterpret_cast<const float4*>(adf + kq * 4);
    float4 vg = *reinterpret_cast<const float4*>(linw + kq * 4);
#pragma unroll
    for (int i = 0; i < 4; ++i) {
        int n = n0 + nq * 4 + i;
        float s = acc[i][0] * va.x + acc[i][1] * va.y + acc[i][2] * va.z + acc[i][3] * va.w;
        float d = acc[i][0] * vd.x + acc[i][1] * vd.y + acc[i][2] * vd.z + acc[i][3] * vd.w;
        float g = acc[i][0] * vg.x + acc[i][1] * vg.y + acc[i][2] * vg.z + acc[i][3] * vg.w;
#pragma unroll
        for (int m = 1; m < 8; m <<= 1) {
            s += __shfl_xor(s, m, 8);
            d += __shfl_xor(d, m, 8);
            g += __shfl_xor(g, m, 8);
        }
        if ((kq & 7) == 0 && n < N_NODES) {
            asg[(size_t)n * 8 + head] = s;
            asg[(size_t)n * 8 + 4 + head] = g;
            adn[(size_t)n * 4 + head] = d;
        }
    }
}

// ---------------------------------------------------------------------------
// K7: layer-2 gather: 16-lane group per node, lanes stride the edge list.
// ---------------------------------------------------------------------------
__global__ void __launch_bounds__(256)
k7_l2(const int* __restrict__ starts, const int* __restrict__ el_src,
      const float4* __restrict__ el_ae2, const float* __restrict__ asg,
      const float* __restrict__ adn, const float* __restrict__ cbias,
      float* __restrict__ out) {
    int t = threadIdx.x;
    int g16 = t & 15;
    int node = blockIdx.x * 16 + (t >> 4);
    if (node >= N_NODES) return;
    int s = starts[node], e = starts[node + 1];
    float4 ad4 = *reinterpret_cast<const float4*>(adn + (size_t)node * 4);
    float4 dsum = make_float4(0, 0, 0, 0);
    float4 gsum = make_float4(0, 0, 0, 0);
    float4 aesum = make_float4(0, 0, 0, 0);
    for (int j = s + g16; j < e; j += 16) {
        int src = el_src[j];
        float4 ae4 = el_ae2[j];
        const float* ap = asg + (size_t)src * 8;
        float4 as4 = *reinterpret_cast<const float4*>(ap);
        float4 g4  = *reinterpret_cast<const float4*>(ap + 4);
        float e0 = __expf(lrelu(as4.x + ad4.x + ae4.x));
        float e1 = __expf(lrelu(as4.y + ad4.y + ae4.y));
        float e2 = __expf(lrelu(as4.z + ad4.z + ae4.z));
        float e3 = __expf(lrelu(as4.w + ad4.w + ae4.w));
        dsum.x += e0; dsum.y += e1; dsum.z += e2; dsum.w += e3;
        gsum.x += e0 * g4.x; gsum.y += e1 * g4.y; gsum.z += e2 * g4.z; gsum.w += e3 * g4.w;
        aesum.x += ae4.x; aesum.y += ae4.y; aesum.z += ae4.z; aesum.w += ae4.w;
    }
#pragma unroll
    for (int m = 1; m < 16; m <<= 1) {
        dsum.x += __shfl_xor(dsum.x, m, 16);  dsum.y += __shfl_xor(dsum.y, m, 16);
        dsum.z += __shfl_xor(dsum.z, m, 16);  dsum.w += __shfl_xor(dsum.w, m, 16);
        gsum.x += __shfl_xor(gsum.x, m, 16);  gsum.y += __shfl_xor(gsum.y, m, 16);
        gsum.z += __shfl_xor(gsum.z, m, 16);  gsum.w += __shfl_xor(gsum.w, m, 16);
        aesum.x += __shfl_xor(aesum.x, m, 16); aesum.y += __shfl_xor(aesum.y, m, 16);
        aesum.z += __shfl_xor(aesum.z, m, 16); aesum.w += __shfl_xor(aesum.w, m, 16);
    }
    if (g16 == 0) {
        float deg = fmaxf((float)(e - s), 1.f);
        const float* ap = asg + (size_t)node * 8;
        float4 mas = *reinterpret_cast<const float4*>(ap);
        float4 mg  = *reinterpret_cast<const float4*>(ap + 4);
        float r = cbias[0];
        float e0;
        e0 = __expf(lrelu(mas.x + ad4.x + aesum.x / deg)); r += (gsum.x + e0 * mg.x) / (dsum.x + e0);
        e0 = __expf(lrelu(mas.y + ad4.y + aesum.y / deg)); r += (gsum.y + e0 * mg.y) / (dsum.y + e0);
        e0 = __expf(lrelu(mas.z + ad4.z + aesum.z / deg)); r += (gsum.z + e0 * mg.z) / (dsum.z + e0);
        e0 = __expf(lrelu(mas.w + ad4.w + aesum.w / deg)); r += (gsum.w + e0 * mg.w) / (dsum.w + e0);
        out[node] = r;
    }
}

// ---------------------------------------------------------------------------
extern "C" void kernel_launch(void* const* d_in, const int* in_sizes, int n_in,
                              void* d_out, int out_size, void* d_ws, size_t ws_size,
                              hipStream_t stream) {
    (void)in_sizes; (void)n_in; (void)out_size;
    const float* x    = (const float*)d_in[0];
    const float* ea   = (const float*)d_in[1];
    const float* W1   = (const float*)d_in[2];
    const float* as1  = (const float*)d_in[3];
    const float* ad1  = (const float*)d_in[4];
    const float* We1  = (const float*)d_in[5];
    const float* ae1  = (const float*)d_in[6];
    const float* b1   = (const float*)d_in[7];
    const float* W2   = (const float*)d_in[8];
    const float* as2  = (const float*)d_in[9];
    const float* ad2  = (const float*)d_in[10];
    const float* We2  = (const float*)d_in[11];
    const float* ae2  = (const float*)d_in[12];
    const float* b2   = (const float*)d_in[13];
    const float* linw = (const float*)d_in[14];
    const float* linb = (const float*)d_in[15];
    const int*   ei   = (const int*)d_in[16];
    float* out = (float*)d_out;
    float* ws  = (float*)d_ws;

    size_t off = 0;
    float* h1p   = ws + off; off += (size_t)N_NODES * K_DIM;
    float* x2    = ws + off; off += (size_t)N_NODES * K_DIM;
    float* asn1  = ws + off; off += (size_t)N_NODES * 4;
    float* adn1  = ws + off; off += (size_t)N_NODES * 4;
    float* asg2  = ws + off; off += (size_t)N_NODES * 8;
    float* adn2  = ws + off; off += (size_t)N_NODES * 4;
    float* vbuf  = ws + off; off += 512;
    float* cbias = ws + off; off += 64;
    int* starts  = (int*)(ws + off); off += (size_t)N_NODES + 8;
    int* cursor  = (int*)(ws + off); off += (size_t)N_NODES;
    int* el_src  = (int*)(ws + off); off += (size_t)N_EDGES;
    float* elae1 = ws + off; off += (size_t)N_EDGES * 4;
    float* elae2 = ws + off; off += (size_t)N_EDGES * 4;
    int* cnt     = (int*)(ws + off); off += (size_t)N_NODES;

    if (ws_size < off * sizeof(float)) return; // workspace too small: fail visibly

    hipMemsetAsync(cnt, 0, N_NODES * sizeof(int), stream);

    k0_fold<<<1, 256, 0, stream>>>(We1, ae1, We2, ae2, b2, linw, linb, vbuf, cbias);
    kc_count<<<(N_EDGES + 255) / 256, 256, 0, stream>>>(ei, cnt);
    k2_scan<<<1, 1024, 0, stream>>>(cnt, starts, cursor);
    k1_edge<<<N_EDGES / 256, 256, 0, stream>>>(ea, ei, vbuf, cursor, el_src,
                                               (float4*)elae1, (float4*)elae2);
    k4_proj1<<<(N_NODES + 31) / 32, 256, 0, stream>>>(x, W1, as1, ad1, h1p, asn1, adn1);
    k5_agg1<<<(N_NODES + 3) / 4, 256, 0, stream>>>(starts, el_src, elae1,
                                                   asn1, adn1, h1p, b1, x2);
    k6_proj2<<<(N_NODES + 31) / 32, 256, 0, stream>>>(x2, W2, as2, ad2, linw, asg2, adn2);
    k7_l2<<<(N_NODES + 15) / 16, 256, 0, stream>>>(starts, el_src, (const float4*)elae2,
                                                   asg2, adn2, cbias, out);
}